// Round 1
// baseline (1093.665 us; speedup 1.0000x reference)
//
#include <hip/hip_runtime.h>
#include <hip/hip_bf16.h>

typedef unsigned short u16;
typedef unsigned int   u32;

typedef __attribute__((ext_vector_type(8))) short bf16x8;  // 8 bf16 = 4 VGPRs
typedef __attribute__((ext_vector_type(4))) float f32x4;   // MFMA 16x16 accum

constexpr int N_AUDIO = 480000;
constexpr int K_IR    = 240000;

// k' (shifted tap index) range needed: [0, K + 15 + 256) = [0, 240271)
constexpr int NSPLIT  = 8;
constexpr int LSPLIT  = 30048;            // 939*32 ; 8*30048 = 240384 >= 240271
constexpr int ITERS   = LSPLIT / 32;      // 939 k-steps per split
constexpr int NGROUP  = 469;              // ceil(480000 / 1024) output groups

// padded bf16 audio: max idx = 479232+512+240+240383 = 720367
constexpr int A_ELEMS = 720896;
// IR phase rows: row p holds ir_p[x] = ir[x-p], x in [-272, ROW_IR-272)
constexpr int IR_PAD  = 272;              // covers -8k_h -256*nt front underrun
constexpr int ROW_IR  = 240704;           // >= 272 + 240384 + 24 + 8, mult of 8
constexpr int IR_ELEMS = 8 * ROW_IR;

// ws layout (bytes), all 16B aligned
constexpr size_t OFF_A   = 0;
constexpr size_t OFF_IR  = (size_t)A_ELEMS * 2;              // 1,441,792
constexpr size_t OFF_ACC = OFF_IR + (size_t)IR_ELEMS * 2;    // +3,851,264
constexpr size_t OFF_MAX = OFF_ACC + (size_t)N_AUDIO * 4;    // +1,920,000

__device__ __forceinline__ u16 f2bf(float f) {
    u32 u = __float_as_uint(f);
    u32 r = (u + 0x7fffu + ((u >> 16) & 1u)) >> 16;   // RTN
    return (u16)r;
}

// ---- kernel 1: convert inputs to bf16 (audio padded, IR in 8 phase rows), zero accum+slot
__global__ void prep_kernel(const float* __restrict__ audio, const float* __restrict__ ir,
                            u16* __restrict__ abuf, u16* __restrict__ irbuf,
                            float* __restrict__ accum, u32* __restrict__ slot) {
    int tid = blockIdx.x * blockDim.x + threadIdx.x;
    int nth = gridDim.x * blockDim.x;
    if (tid == 0) *slot = 0u;
    for (int i = tid; i < A_ELEMS; i += nth)
        abuf[i] = (i < N_AUDIO) ? f2bf(audio[i]) : (u16)0;
    for (int i = tid; i < IR_ELEMS; i += nth) {
        int p = i / ROW_IR;               // phase 0..7
        int x = (i - p * ROW_IR) - IR_PAD;
        int src = x - p;
        irbuf[i] = (src >= 0 && src < K_IR) ? f2bf(ir[src]) : (u16)0;
    }
    for (int i = tid; i < N_AUDIO; i += nth) accum[i] = 0.0f;
}

// ---- kernel 2: MFMA correlation, MT=2 x NT=2 tiles/wave, split-K via atomicAdd
// C[m][n] = out[base + 16m + n]; A[m][k'] = audio[base + 16m + k'] (aligned);
// B[k'][n] = ir[k' - n - 256*nt] read from phase row (n&7) at aligned offset.
__global__ __launch_bounds__(256) void conv_kernel(const u16* __restrict__ abuf,
                                                   const u16* __restrict__ irbuf,
                                                   float* __restrict__ accum) {
    const int wave = threadIdx.x >> 6;
    const int lane = threadIdx.x & 63;
    const int gid  = blockIdx.x * 4 + wave;          // 0..3751
    const int s    = gid / NGROUP;                   // k-split 0..7
    const int g    = gid - s * NGROUP;               // output group 0..468

    const int m16 = lane & 15;                       // A row m / B col n / C col
    const int kq  = lane >> 4;                       // 0..3 (k-chunk quadrant)
    const int nh  = m16 >> 3;                        // n high bit
    const int ph  = m16 & 7;                         // IR phase row

    const int gbase = g * 1024;
    const int k0    = s * LSPLIT;

    const u16* aptr = abuf + gbase + 16 * m16 + 8 * kq + k0;
    const u16* bptr = irbuf + ph * ROW_IR + IR_PAD + k0 + 8 * (kq - nh);

    f32x4 acc00 = {0.f,0.f,0.f,0.f}, acc01 = {0.f,0.f,0.f,0.f};
    f32x4 acc10 = {0.f,0.f,0.f,0.f}, acc11 = {0.f,0.f,0.f,0.f};

    for (int it = 0; it < ITERS; ++it) {
        bf16x8 b0 = *(const bf16x8*)(bptr);          // nt=0
        bf16x8 b1 = *(const bf16x8*)(bptr - 256);    // nt=1 (shift 256 taps)
        bf16x8 a0 = *(const bf16x8*)(aptr);          // mt=0
        bf16x8 a1 = *(const bf16x8*)(aptr + 512);    // mt=1
        acc00 = __builtin_amdgcn_mfma_f32_16x16x32_bf16(a0, b0, acc00, 0, 0, 0);
        acc01 = __builtin_amdgcn_mfma_f32_16x16x32_bf16(a0, b1, acc01, 0, 0, 0);
        acc10 = __builtin_amdgcn_mfma_f32_16x16x32_bf16(a1, b0, acc10, 0, 0, 0);
        acc11 = __builtin_amdgcn_mfma_f32_16x16x32_bf16(a1, b1, acc11, 0, 0, 0);
        aptr += 32;
        bptr += 32;
    }

    // C/D layout: col = lane&15, row = (lane>>4)*4 + r  ->  t = base + 16*row + col
    #pragma unroll
    for (int mt = 0; mt < 2; ++mt) {
        #pragma unroll
        for (int nt = 0; nt < 2; ++nt) {
            const f32x4& a = (mt == 0) ? (nt == 0 ? acc00 : acc01)
                                       : (nt == 0 ? acc10 : acc11);
            int base = gbase + 512 * mt + 256 * nt + 64 * kq + m16;
            #pragma unroll
            for (int r = 0; r < 4; ++r) {
                int t = base + 16 * r;
                if (t < N_AUDIO) atomicAdd(&accum[t], a[r]);
            }
        }
    }
}

// ---- kernel 3: global abs-max (float-bits atomicMax works for non-negative floats)
__global__ __launch_bounds__(256) void reduce_max_kernel(const float* __restrict__ accum,
                                                         u32* __restrict__ slot) {
    int tid = blockIdx.x * blockDim.x + threadIdx.x;
    int nth = gridDim.x * blockDim.x;
    float m = 0.f;
    for (int i = tid; i < N_AUDIO; i += nth) m = fmaxf(m, fabsf(accum[i]));
    for (int off = 32; off > 0; off >>= 1) m = fmaxf(m, __shfl_down(m, off, 64));
    __shared__ float smax[4];
    if ((threadIdx.x & 63) == 0) smax[threadIdx.x >> 6] = m;
    __syncthreads();
    if (threadIdx.x == 0) {
        float b = fmaxf(fmaxf(smax[0], smax[1]), fmaxf(smax[2], smax[3]));
        atomicMax(slot, __float_as_uint(b));
    }
}

// ---- kernel 4: normalize
__global__ __launch_bounds__(256) void scale_kernel(const float* __restrict__ accum,
                                                    const u32* __restrict__ slot,
                                                    float* __restrict__ out) {
    float inv = 1.0f / __uint_as_float(*slot);
    int t = blockIdx.x * 256 + threadIdx.x;
    if (t < N_AUDIO) out[t] = accum[t] * inv;
}

extern "C" void kernel_launch(void* const* d_in, const int* in_sizes, int n_in,
                              void* d_out, int out_size, void* d_ws, size_t ws_size,
                              hipStream_t stream) {
    const float* audio = (const float*)d_in[0];
    const float* ir    = (const float*)d_in[1];
    float* out = (float*)d_out;

    char* ws = (char*)d_ws;
    u16*   abuf  = (u16*)(ws + OFF_A);
    u16*   irbuf = (u16*)(ws + OFF_IR);
    float* accum = (float*)(ws + OFF_ACC);
    u32*   slot  = (u32*)(ws + OFF_MAX);

    prep_kernel<<<2048, 256, 0, stream>>>(audio, ir, abuf, irbuf, accum, slot);
    conv_kernel<<<NGROUP * NSPLIT / 4, 256, 0, stream>>>(abuf, irbuf, accum);
    reduce_max_kernel<<<960, 256, 0, stream>>>(accum, slot);
    scale_kernel<<<(N_AUDIO + 255) / 256, 256, 0, stream>>>(accum, slot, out);
}

// Round 2
// 585.938 us; speedup vs baseline: 1.8665x; 1.8665x over previous
//
#include <hip/hip_runtime.h>
#include <hip/hip_bf16.h>

typedef unsigned short u16;
typedef unsigned int   u32;

typedef __attribute__((ext_vector_type(8))) short bf16x8;  // 8 bf16 = 4 VGPRs
typedef __attribute__((ext_vector_type(4))) float f32x4;   // MFMA 16x16 accum

constexpr int N_AUDIO = 480000;
constexpr int K_IR    = 240000;

// k' (shifted tap index) range needed: [0, K + 15 + 256) = [0, 240271)
constexpr int NSPLIT  = 32;
constexpr int LSPLIT  = 7520;             // mult of 32; 32*7520 = 240640 >= 240271
constexpr int ITERS   = LSPLIT / 32;      // 235 k-steps per split
constexpr int NGROUP  = 469;              // ceil(480000 / 1024) output groups

// padded bf16 audio: max read = 479232+240+24+233120+7488+8 = 720112
constexpr int A_ELEMS = 720896;
// IR phase rows: row p holds ir_p[x] = ir[x-p], x in [-IR_PAD, ROW_IR-IR_PAD)
constexpr int IR_PAD  = 272;
constexpr int ROW_IR  = 241024;           // >= 272+233120+7488+32 = 240912, mult of 8
constexpr int IR_ELEMS = 8 * ROW_IR;      // 1,928,192

// ws layout (bytes), all 16B aligned
constexpr size_t OFF_A   = 0;
constexpr size_t OFF_IR  = (size_t)A_ELEMS * 2;              // 1,441,792
constexpr size_t OFF_ACC = OFF_IR + (size_t)IR_ELEMS * 2;    // +3,856,384
constexpr size_t OFF_MAX = OFF_ACC + (size_t)N_AUDIO * 4;    // +1,920,000

__device__ __forceinline__ u16 f2bf(float f) {
    u32 u = __float_as_uint(f);
    u32 r = (u + 0x7fffu + ((u >> 16) & 1u)) >> 16;   // RTN
    return (u16)r;
}

// ---- kernel 1: convert inputs to bf16 (audio padded, IR in 8 phase rows), zero accum+slot
__global__ void prep_kernel(const float* __restrict__ audio, const float* __restrict__ ir,
                            u16* __restrict__ abuf, u16* __restrict__ irbuf,
                            float* __restrict__ accum, u32* __restrict__ slot) {
    int tid = blockIdx.x * blockDim.x + threadIdx.x;
    int nth = gridDim.x * blockDim.x;
    if (tid == 0) *slot = 0u;
    for (int i = tid; i < A_ELEMS; i += nth)
        abuf[i] = (i < N_AUDIO) ? f2bf(audio[i]) : (u16)0;
    for (int i = tid; i < IR_ELEMS; i += nth) {
        int p = i / ROW_IR;               // phase 0..7
        int x = (i - p * ROW_IR) - IR_PAD;
        int src = x - p;
        irbuf[i] = (src >= 0 && src < K_IR) ? f2bf(ir[src]) : (u16)0;
    }
    for (int i = tid; i < N_AUDIO; i += nth) accum[i] = 0.0f;
}

// ---- kernel 2: MFMA correlation, MT=2 x NT=2 tiles/wave, split-K via atomicAdd
// C[m][n] = out[base + 16m + n]; A[m][k'] = audio[base + 16m + k'] (aligned);
// B[k'][n] = ir[k' - n - 256*nt] read from phase row (n&7) at aligned offset.
__global__ __launch_bounds__(256) void conv_kernel(const u16* __restrict__ abuf,
                                                   const u16* __restrict__ irbuf,
                                                   float* __restrict__ accum) {
    const int wave = threadIdx.x >> 6;
    const int lane = threadIdx.x & 63;
    const int gid  = blockIdx.x * 4 + wave;          // 0..15007
    const int s    = gid / NGROUP;                   // k-split 0..31
    const int g    = gid - s * NGROUP;               // output group 0..468

    const int m16 = lane & 15;                       // A row m / B col n / C col
    const int kq  = lane >> 4;                       // 0..3 (k-chunk quadrant)
    const int nh  = m16 >> 3;                        // n high bit
    const int ph  = m16 & 7;                         // IR phase row

    const int gbase = g * 1024;
    const int k0    = s * LSPLIT;

    const u16* aptr = abuf + gbase + 16 * m16 + 8 * kq + k0;
    const u16* bptr = irbuf + ph * ROW_IR + IR_PAD + k0 + 8 * (kq - nh);

    f32x4 acc00 = {0.f,0.f,0.f,0.f}, acc01 = {0.f,0.f,0.f,0.f};
    f32x4 acc10 = {0.f,0.f,0.f,0.f}, acc11 = {0.f,0.f,0.f,0.f};

    #pragma unroll 2
    for (int it = 0; it < ITERS; ++it) {
        bf16x8 b0 = *(const bf16x8*)(bptr);          // nt=0
        bf16x8 b1 = *(const bf16x8*)(bptr - 256);    // nt=1 (shift 256 taps)
        bf16x8 a0 = *(const bf16x8*)(aptr);          // mt=0
        bf16x8 a1 = *(const bf16x8*)(aptr + 512);    // mt=1
        acc00 = __builtin_amdgcn_mfma_f32_16x16x32_bf16(a0, b0, acc00, 0, 0, 0);
        acc01 = __builtin_amdgcn_mfma_f32_16x16x32_bf16(a0, b1, acc01, 0, 0, 0);
        acc10 = __builtin_amdgcn_mfma_f32_16x16x32_bf16(a1, b0, acc10, 0, 0, 0);
        acc11 = __builtin_amdgcn_mfma_f32_16x16x32_bf16(a1, b1, acc11, 0, 0, 0);
        aptr += 32;
        bptr += 32;
    }

    // C/D layout: col = lane&15, row = (lane>>4)*4 + r  ->  t = base + 16*row + col
    #pragma unroll
    for (int mt = 0; mt < 2; ++mt) {
        #pragma unroll
        for (int nt = 0; nt < 2; ++nt) {
            const f32x4& a = (mt == 0) ? (nt == 0 ? acc00 : acc01)
                                       : (nt == 0 ? acc10 : acc11);
            int base = gbase + 512 * mt + 256 * nt + 64 * kq + m16;
            #pragma unroll
            for (int r = 0; r < 4; ++r) {
                int t = base + 16 * r;
                if (t < N_AUDIO) atomicAdd(&accum[t], a[r]);
            }
        }
    }
}

// ---- kernel 3: global abs-max (float-bits atomicMax works for non-negative floats)
__global__ __launch_bounds__(256) void reduce_max_kernel(const float* __restrict__ accum,
                                                         u32* __restrict__ slot) {
    int tid = blockIdx.x * blockDim.x + threadIdx.x;
    int nth = gridDim.x * blockDim.x;
    float m = 0.f;
    for (int i = tid; i < N_AUDIO; i += nth) m = fmaxf(m, fabsf(accum[i]));
    for (int off = 32; off > 0; off >>= 1) m = fmaxf(m, __shfl_down(m, off, 64));
    __shared__ float smax[4];
    if ((threadIdx.x & 63) == 0) smax[threadIdx.x >> 6] = m;
    __syncthreads();
    if (threadIdx.x == 0) {
        float b = fmaxf(fmaxf(smax[0], smax[1]), fmaxf(smax[2], smax[3]));
        atomicMax(slot, __float_as_uint(b));
    }
}

// ---- kernel 4: normalize
__global__ __launch_bounds__(256) void scale_kernel(const float* __restrict__ accum,
                                                    const u32* __restrict__ slot,
                                                    float* __restrict__ out) {
    float inv = 1.0f / __uint_as_float(*slot);
    int t = blockIdx.x * 256 + threadIdx.x;
    if (t < N_AUDIO) out[t] = accum[t] * inv;
}

extern "C" void kernel_launch(void* const* d_in, const int* in_sizes, int n_in,
                              void* d_out, int out_size, void* d_ws, size_t ws_size,
                              hipStream_t stream) {
    const float* audio = (const float*)d_in[0];
    const float* ir    = (const float*)d_in[1];
    float* out = (float*)d_out;

    char* ws = (char*)d_ws;
    u16*   abuf  = (u16*)(ws + OFF_A);
    u16*   irbuf = (u16*)(ws + OFF_IR);
    float* accum = (float*)(ws + OFF_ACC);
    u32*   slot  = (u32*)(ws + OFF_MAX);

    prep_kernel<<<2048, 256, 0, stream>>>(audio, ir, abuf, irbuf, accum, slot);
    conv_kernel<<<NGROUP * NSPLIT / 4, 256, 0, stream>>>(abuf, irbuf, accum);
    reduce_max_kernel<<<960, 256, 0, stream>>>(accum, slot);
    scale_kernel<<<(N_AUDIO + 255) / 256, 256, 0, stream>>>(accum, slot, out);
}